// Round 4
// baseline (1024.379 us; speedup 1.0000x reference)
//
#include <hip/hip_runtime.h>
#include <hip/hip_bf16.h>

#define THRESH 1373
typedef unsigned short ushort_t;
typedef __bf16 bf16x8 __attribute__((ext_vector_type(8)));
typedef float f32x4 __attribute__((ext_vector_type(4)));

static __device__ __forceinline__ ushort_t f2bf(float x) {
    unsigned u = __float_as_uint(x);
    unsigned r = (u + 0x7fffu + ((u >> 16) & 1u)) >> 16;  // RNE
    return (ushort_t)r;
}

// ---------------------------------------------------------------------------
// Kernel A: front-end. Computes f[B,128] (bf16) into workspace.
//   V_src = ent[src] + W_V @ (sum_n tn_n) + 10*b_V        (softmax(axis=1)==1!)
//   z = [V_src, rel_embed[rel]];  h = relu(fc1 z);  f = fc2 h
// 8 batch elements per block; all LDS reads in inner loops are broadcasts.
// ---------------------------------------------------------------------------
__global__ __launch_bounds__(128) void f_kernel(
    const int* __restrict__ src, const int* __restrict__ rel,
    const int* __restrict__ t_idxs, const float* __restrict__ ent,
    const float* __restrict__ rel_embed, const float* __restrict__ nod,
    const float* __restrict__ W_V, const float* __restrict__ b_V,
    const float* __restrict__ fc1_w, const float* __restrict__ fc1_b,
    const float* __restrict__ fc2_w, const float* __restrict__ fc2_b,
    ushort_t* __restrict__ f_out)
{
    const int BB = 8;
    __shared__ float tn[BB][160];
    __shared__ float z[BB][256];
    __shared__ float h[BB][128];
    __shared__ int   sS[BB];

    const int tid = threadIdx.x;           // 0..127
    const int b0  = blockIdx.x * BB;

    if (tid < BB) sS[tid] = src[b0 + tid];
    __syncthreads();

    for (int bb = 0; bb < BB; ++bb) {
        const int s = sS[bb];
        float sum = 0.f; int cge = 0;
        #pragma unroll
        for (int n = 0; n < 10; ++n) {
            const int ng = t_idxs[s * 10 + n];      // uniform -> scalar load
            sum += ent[(size_t)ng * 128 + tid];     // coalesced row gather
            cge += (ng >= THRESH) ? 1 : 0;
        }
        tn[bb][tid] = sum;
        if (tid < 32)
            tn[bb][128 + tid] = (float)(10 - cge) * nod[tid]
                              + (float)cge        * nod[32 + tid];
    }
    __syncthreads();

    {   // V_src and z
        float acc[BB];
        #pragma unroll
        for (int bb = 0; bb < BB; ++bb) acc[bb] = 10.f * b_V[tid];
        for (int i = 0; i < 160; ++i) {
            const float w = W_V[tid * 160 + i];
            #pragma unroll
            for (int bb = 0; bb < BB; ++bb) acc[bb] += w * tn[bb][i];
        }
        #pragma unroll
        for (int bb = 0; bb < BB; ++bb) {
            z[bb][tid]       = ent[(size_t)sS[bb] * 128 + tid] + acc[bb];
            z[bb][128 + tid] = rel_embed[rel[b0 + bb] * 128 + tid];
        }
    }
    __syncthreads();

    {   // h = relu(fc1 z)
        float acc[BB];
        #pragma unroll
        for (int bb = 0; bb < BB; ++bb) acc[bb] = fc1_b[tid];
        for (int i = 0; i < 256; ++i) {
            const float w = fc1_w[tid * 256 + i];
            #pragma unroll
            for (int bb = 0; bb < BB; ++bb) acc[bb] += w * z[bb][i];
        }
        #pragma unroll
        for (int bb = 0; bb < BB; ++bb) h[bb][tid] = fmaxf(acc[bb], 0.f);
    }
    __syncthreads();

    {   // f = fc2 h  -> bf16
        float acc[BB];
        #pragma unroll
        for (int bb = 0; bb < BB; ++bb) acc[bb] = fc2_b[tid];
        for (int i = 0; i < 128; ++i) {
            const float w = fc2_w[tid * 128 + i];
            #pragma unroll
            for (int bb = 0; bb < BB; ++bb) acc[bb] += w * h[bb][i];
        }
        #pragma unroll
        for (int bb = 0; bb < BB; ++bb)
            f_out[(size_t)(b0 + bb) * 128 + tid] = f2bf(acc[bb]);
    }
}

// ---------------------------------------------------------------------------
// Kernel B: out[m][n] = sigmoid( sum_k f[m][k] * E[n][k] ), M=2048 N=100000 K=128
// Per block: 64 E-rows staged f32->bf16 into XOR-swizzled LDS; 16 B-frags
// hoisted to registers; loop M in 256-row steps (4 waves x 64 rows),
// mfma_f32_16x16x32_bf16, sigmoid, nontemporal f32 stores.
// ---------------------------------------------------------------------------
#define BN 64
#define NENT 100000
#define MTOT 2048

__global__ __launch_bounds__(256) void gemm_sig(
    const float* __restrict__ ent, const ushort_t* __restrict__ fbf,
    float* __restrict__ out)
{
    __shared__ __align__(16) ushort_t lE[BN * 128];

    const int tid  = threadIdx.x;
    const int n0   = blockIdx.x * BN;
    const int lane = tid & 63;
    const int wv   = tid >> 6;
    const int r    = lane & 15;     // row-in-16 / col-in-16
    const int kq   = lane >> 4;     // 0..3, k-quarter / row-quad

    // ---- stage E tile: 64 rows x 128 cols, f32 -> bf16, swizzled ----
    #pragma unroll
    for (int it = 0; it < 8; ++it) {
        const int idx = it * 256 + tid;        // 0..2047
        const int row = idx >> 5;              // 0..63
        const int c4  = idx & 31;              // float4 index in row
        const int gr  = n0 + row;
        float4 v;
        if (gr < NENT) v = *(const float4*)(ent + (size_t)gr * 128 + c4 * 4);
        else           v = make_float4(0.f, 0.f, 0.f, 0.f);
        ushort_t u4[4] = { f2bf(v.x), f2bf(v.y), f2bf(v.z), f2bf(v.w) };
        int off = row * 256 + c4 * 8;          // byte offset in tile
        off ^= (row & 7) << 4;                 // bank-conflict swizzle
        *(ushort4*)((char*)lE + off) = *(const ushort4*)u4;
    }
    __syncthreads();

    // ---- hoist all B fragments: [ns][ks], each 8 bf16 ----
    bf16x8 bfr[4][4];
    #pragma unroll
    for (int ns = 0; ns < 4; ++ns)
        #pragma unroll
        for (int ks = 0; ks < 4; ++ks) {
            const int row  = ns * 16 + r;
            int off = row * 256 + (ks * 32 + kq * 8) * 2;
            off ^= (row & 7) << 4;
            bfr[ns][ks] = *(const bf16x8*)((char*)lE + off);
        }

    // ---- M loop: each wave owns 64 rows per 256-row step ----
    for (int m0 = wv * 64; m0 < MTOT; m0 += 256) {
        f32x4 acc[4][4];
        #pragma unroll
        for (int ms = 0; ms < 4; ++ms)
            #pragma unroll
            for (int ns = 0; ns < 4; ++ns)
                acc[ms][ns] = f32x4{0.f, 0.f, 0.f, 0.f};

        #pragma unroll
        for (int ks = 0; ks < 4; ++ks) {
            bf16x8 afr[4];
            #pragma unroll
            for (int ms = 0; ms < 4; ++ms) {
                const int mrow = m0 + ms * 16 + r;
                afr[ms] = *(const bf16x8*)(fbf + (size_t)mrow * 128 + ks * 32 + kq * 8);
            }
            #pragma unroll
            for (int ms = 0; ms < 4; ++ms)
                #pragma unroll
                for (int ns = 0; ns < 4; ++ns)
                    acc[ms][ns] = __builtin_amdgcn_mfma_f32_16x16x32_bf16(
                        afr[ms], bfr[ns][ks], acc[ms][ns], 0, 0, 0);
        }

        // ---- epilogue: sigmoid + nontemporal store ----
        #pragma unroll
        for (int ms = 0; ms < 4; ++ms) {
            const int mrow = m0 + ms * 16 + kq * 4;   // D row = (lane>>4)*4+reg
            #pragma unroll
            for (int ns = 0; ns < 4; ++ns) {
                const int col = n0 + ns * 16 + r;     // D col = lane&15
                if (col < NENT) {
                    #pragma unroll
                    for (int rr = 0; rr < 4; ++rr) {
                        const float x  = acc[ms][ns][rr];
                        const float sg = 1.f / (1.f + __expf(-x));
                        __builtin_nontemporal_store(
                            sg, out + (size_t)(mrow + rr) * NENT + col);
                    }
                }
            }
        }
    }
}

extern "C" void kernel_launch(void* const* d_in, const int* in_sizes, int n_in,
                              void* d_out, int out_size, void* d_ws, size_t ws_size,
                              hipStream_t stream) {
    const int*   src    = (const int*)  d_in[0];
    const int*   rel    = (const int*)  d_in[1];
    const int*   t_idxs = (const int*)  d_in[2];
    const float* ent    = (const float*)d_in[3];
    const float* rel_e  = (const float*)d_in[4];
    const float* nod    = (const float*)d_in[5];
    // d_in[6..9] = W_Q, b_Q, W_K, b_K : provably dead (softmax over singleton axis)
    const float* W_V    = (const float*)d_in[10];
    const float* b_V    = (const float*)d_in[11];
    const float* fc1_w  = (const float*)d_in[12];
    const float* fc1_b  = (const float*)d_in[13];
    const float* fc2_w  = (const float*)d_in[14];
    const float* fc2_b  = (const float*)d_in[15];

    float*    out = (float*)d_out;
    ushort_t* fbf = (ushort_t*)d_ws;   // f as bf16: 2048*128*2 = 512 KB

    hipLaunchKernelGGL(f_kernel, dim3(2048 / 8), dim3(128), 0, stream,
                       src, rel, t_idxs, ent, rel_e, nod,
                       W_V, b_V, fc1_w, fc1_b, fc2_w, fc2_b, fbf);

    const int nblocks = (NENT + BN - 1) / BN;   // 1563
    hipLaunchKernelGGL(gemm_sig, dim3(nblocks), dim3(256), 0, stream,
                       ent, fbf, out);
}